// Round 1
// baseline (121.081 us; speedup 1.0000x reference)
//
#include <hip/hip_runtime.h>

#define MDIM 4096
#define NDIM 4096
#define NCOEF 768
#define ALPHA 16.0f

typedef __attribute__((ext_vector_type(8))) short bf16x8;
typedef __attribute__((ext_vector_type(4))) float f32x4;

__device__ __forceinline__ unsigned short f2bf(float x) {
    unsigned u = __float_as_uint(x);
    u += 0x7FFFu + ((u >> 16) & 1u);
    return (unsigned short)(u >> 16);
}

// ---- kernel 0: per-coefficient metadata (r, c, scales, dedup) ----
__global__ void meta_kernel(const int* __restrict__ fidx,
                            const float* __restrict__ dw,
                            int* __restrict__ r_m, int* __restrict__ c_m,
                            float* __restrict__ su_m, float* __restrict__ sv_m)
{
    __shared__ int idx_s[NCOEF];
    const int p = threadIdx.x;
    idx_s[p] = fidx[p];
    __syncthreads();
    const int idx = idx_s[p];
    const int r = idx >> 12;          // / 4096
    const int c = idx & (NDIM - 1);   // % 4096
    // .at[].set semantics: last write wins -> kill earlier duplicates
    float keep = 1.0f;
    for (int q = p + 1; q < NCOEF; ++q)
        if (idx_s[q] == idx) { keep = 0.0f; break; }
    const float s0 = 0.015625f;              // sqrt(1/4096)
    const float s1 = 0.022097086912079612f;  // sqrt(2/4096)
    r_m[p] = r;
    c_m[p] = c;
    su_m[p] = (r == 0) ? s0 : s1;
    sv_m[p] = keep * ALPHA * dw[p] * ((c == 0) ? s0 : s1);
}

// ---- kernel 1: materialize U[i,p] and V[j,p] in bf16 ----
// U[i,p] = s(r_p) * cos(pi*(2i+1)*r_p/8192); integer-exact range reduction.
__global__ __launch_bounds__(256) void fill_uv(
    const int* __restrict__ r_m, const int* __restrict__ c_m,
    const float* __restrict__ su_m, const float* __restrict__ sv_m,
    unsigned short* __restrict__ U, unsigned short* __restrict__ V)
{
    const int b = blockIdx.x;
    const int i = b / 3;                       // row index 0..4095
    const int p = (b % 3) * 256 + threadIdx.x; // coef index 0..767
    const unsigned t = 2u * (unsigned)i + 1u;
    const float w = 3.14159265358979323846f / 8192.0f;
    const unsigned nu = (t * (unsigned)r_m[p]) & 16383u;
    const unsigned nv = (t * (unsigned)c_m[p]) & 16383u;
    const float u = su_m[p] * cosf((float)nu * w);
    const float v = sv_m[p] * cosf((float)nv * w);
    const size_t o = (size_t)i * NCOEF + p;
    U[o] = f2bf(u);
    V[o] = f2bf(v);
}

// ---- kernel 2: out = W + U @ V^T  (M=N=4096, K=768) ----
// 128x128 tile, BK=32, 4 waves (2x2), each wave 64x64 = 4x4 frags of 16x16x32.
__global__ __launch_bounds__(256, 2) void gemm_kernel(
    const float* __restrict__ W,
    const unsigned short* __restrict__ U,
    const unsigned short* __restrict__ V,
    float* __restrict__ out)
{
    __shared__ unsigned short At[128 * 32];  // [row][k] row-major
    __shared__ unsigned short Bt[128 * 32];  // [col][k] row-major (B^T form)

    const int tid = threadIdx.x;
    const int lane = tid & 63;
    const int wave = tid >> 6;

    // XCD-aware swizzle: 1024 blocks, 8 XCDs, 128 contiguous per XCD (bijective)
    const int bid = blockIdx.x;
    const int swz = (bid & 7) * 128 + (bid >> 3);
    const int by = swz >> 5;
    const int bx = swz & 31;
    const int brow = by * 128;
    const int bcol = bx * 128;
    const int wr = wave >> 1;
    const int wc = wave & 1;

    f32x4 acc[4][4] = {};

    // staging: chunk c in [0,512): row=c>>2, k-sub=(c&3)*8; two loads per thread
    const int c0 = tid, c1 = 256 + tid;
    const size_t aOff0 = (size_t)(brow + (c0 >> 2)) * NCOEF + ((c0 & 3) << 3);
    const size_t aOff1 = (size_t)(brow + (c1 >> 2)) * NCOEF + ((c1 & 3) << 3);
    const size_t bOff0 = (size_t)(bcol + (c0 >> 2)) * NCOEF + ((c0 & 3) << 3);
    const size_t bOff1 = (size_t)(bcol + (c1 >> 2)) * NCOEF + ((c1 & 3) << 3);
    // wave-uniform LDS dests (HW adds lane*16B)
    unsigned short* dA0 = At + (wave << 9);
    unsigned short* dA1 = At + 2048 + (wave << 9);
    unsigned short* dB0 = Bt + (wave << 9);
    unsigned short* dB1 = Bt + 2048 + (wave << 9);

    // fragment read addresses: A lane holds row=lane&15, k=(lane>>4)*8 ..+8
    const int fr = lane & 15;
    const int fk = (lane >> 4) << 3;
    const unsigned short* aRd = At + ((wr * 64 + fr) * 32 + fk);
    const unsigned short* bRd = Bt + ((wc * 64 + fr) * 32 + fk);

    for (int k0 = 0; k0 < NCOEF; k0 += 32) {
        __builtin_amdgcn_global_load_lds(
            (const __attribute__((address_space(1))) void*)(U + aOff0 + k0),
            (__attribute__((address_space(3))) void*)dA0, 16, 0, 0);
        __builtin_amdgcn_global_load_lds(
            (const __attribute__((address_space(1))) void*)(U + aOff1 + k0),
            (__attribute__((address_space(3))) void*)dA1, 16, 0, 0);
        __builtin_amdgcn_global_load_lds(
            (const __attribute__((address_space(1))) void*)(V + bOff0 + k0),
            (__attribute__((address_space(3))) void*)dB0, 16, 0, 0);
        __builtin_amdgcn_global_load_lds(
            (const __attribute__((address_space(1))) void*)(V + bOff1 + k0),
            (__attribute__((address_space(3))) void*)dB1, 16, 0, 0);
        __syncthreads();  // compiler drains vmcnt before barrier

        bf16x8 a[4], b[4];
        #pragma unroll
        for (int f = 0; f < 4; ++f) {
            a[f] = *(const bf16x8*)(aRd + f * 16 * 32);
            b[f] = *(const bf16x8*)(bRd + f * 16 * 32);
        }
        #pragma unroll
        for (int fm = 0; fm < 4; ++fm)
            #pragma unroll
            for (int fn = 0; fn < 4; ++fn)
                acc[fm][fn] = __builtin_amdgcn_mfma_f32_16x16x32_bf16(
                    a[fm], b[fn], acc[fm][fn], 0, 0, 0);
        __syncthreads();  // protect LDS before next stage
    }

    // epilogue: out = W + acc  (alpha folded into V)
    // C/D layout: col = lane&15, row = (lane>>4)*4 + reg
    const int col0 = bcol + wc * 64 + fr;
    const int row0 = brow + wr * 64 + ((lane >> 4) << 2);
    #pragma unroll
    for (int fm = 0; fm < 4; ++fm) {
        #pragma unroll
        for (int fn = 0; fn < 4; ++fn) {
            const int cc = col0 + fn * 16;
            const int rr = row0 + fm * 16;
            #pragma unroll
            for (int j = 0; j < 4; ++j) {
                const size_t o = (size_t)(rr + j) * NDIM + cc;
                out[o] = W[o] + acc[fm][fn][j];
            }
        }
    }
}

extern "C" void kernel_launch(void* const* d_in, const int* in_sizes, int n_in,
                              void* d_out, int out_size, void* d_ws, size_t ws_size,
                              hipStream_t stream) {
    const float* weight = (const float*)d_in[0];
    const float* dw     = (const float*)d_in[1];
    const int*   fidx   = (const int*)d_in[2];
    float* out = (float*)d_out;

    char* ws = (char*)d_ws;
    unsigned short* U = (unsigned short*)ws;                       // 6,291,456 B
    unsigned short* V = (unsigned short*)(ws + 6291456);           // 6,291,456 B
    char* meta = ws + 2 * 6291456;
    int*   r_m  = (int*)(meta);
    int*   c_m  = (int*)(meta + NCOEF * 4);
    float* su_m = (float*)(meta + NCOEF * 8);
    float* sv_m = (float*)(meta + NCOEF * 12);

    meta_kernel<<<1, NCOEF, 0, stream>>>(fidx, dw, r_m, c_m, su_m, sv_m);
    fill_uv<<<MDIM * 3, 256, 0, stream>>>(r_m, c_m, su_m, sv_m, U, V);
    gemm_kernel<<<1024, 256, 0, stream>>>(weight, U, V, out);
}

// Round 2
// 100.003 us; speedup vs baseline: 1.2108x; 1.2108x over previous
//
#include <hip/hip_runtime.h>

#define MDIM 4096
#define NDIM 4096
#define NCOEF 768
#define ALPHA 16.0f

typedef __attribute__((ext_vector_type(8))) short bf16x8;
typedef __attribute__((ext_vector_type(4))) float f32x4;

__device__ __forceinline__ unsigned short f2bf(float x) {
    unsigned u = __float_as_uint(x);
    u += 0x7FFFu + ((u >> 16) & 1u);
    return (unsigned short)(u >> 16);
}

// ---- kernel 0: per-coefficient metadata (r, c, scales, dedup) ----
__global__ void meta_kernel(const int* __restrict__ fidx,
                            const float* __restrict__ dw,
                            int* __restrict__ r_m, int* __restrict__ c_m,
                            float* __restrict__ su_m, float* __restrict__ sv_m)
{
    __shared__ int idx_s[NCOEF];
    const int p = threadIdx.x;
    idx_s[p] = fidx[p];
    __syncthreads();
    const int idx = idx_s[p];
    // .at[].set semantics: last write wins -> kill earlier duplicates.
    // Uniform q => LDS broadcast read, pipelined (no break, no divergence).
    int keep = 1;
    #pragma unroll 16
    for (int q = 0; q < NCOEF; ++q)
        keep &= (q <= p) | (idx_s[q] != idx);
    const int r = idx >> 12;          // / 4096
    const int c = idx & (NDIM - 1);   // % 4096
    const float s0 = 0.015625f;              // sqrt(1/4096)
    const float s1 = 0.022097086912079612f;  // sqrt(2/4096)
    r_m[p] = r;
    c_m[p] = c;
    su_m[p] = (r == 0) ? s0 : s1;
    sv_m[p] = (float)keep * ALPHA * dw[p] * ((c == 0) ? s0 : s1);
}

// ---- kernel 1: materialize U[i,p] and V[j,p] in bf16 ----
// U[i,p] = s(r_p) * cos(pi*(2i+1)*r_p/8192); integer-exact range reduction.
__global__ __launch_bounds__(256) void fill_uv(
    const int* __restrict__ r_m, const int* __restrict__ c_m,
    const float* __restrict__ su_m, const float* __restrict__ sv_m,
    unsigned short* __restrict__ U, unsigned short* __restrict__ V)
{
    const int b = blockIdx.x;
    const int i = b / 3;                       // row index 0..4095
    const int p = (b % 3) * 256 + threadIdx.x; // coef index 0..767
    const unsigned t = 2u * (unsigned)i + 1u;
    const float w = 3.14159265358979323846f / 8192.0f;
    const unsigned nu = (t * (unsigned)r_m[p]) & 16383u;
    const unsigned nv = (t * (unsigned)c_m[p]) & 16383u;
    const float u = su_m[p] * cosf((float)nu * w);
    const float v = sv_m[p] * cosf((float)nv * w);
    const size_t o = (size_t)i * NCOEF + p;
    U[o] = f2bf(u);
    V[o] = f2bf(v);
}

// ---- kernel 2: out = W + U @ V^T  (M=N=4096, K=768) ----
// 128x128 tile, BK=32, 4 waves (2x2), each wave 64x64 = 4x4 frags of 16x16x32.
// LDS layout is k-outer: 16B unit (row, ks) lives at chunk index ks*128+row,
// so fragment reads (16 lanes x consecutive rows) are 256B-contiguous ->
// bank-conflict-free. global_load_lds dest stays linear; the permutation is
// carried by the per-lane GLOBAL source address (guideline 21).
__global__ __launch_bounds__(256, 2) void gemm_kernel(
    const float* __restrict__ W,
    const unsigned short* __restrict__ U,
    const unsigned short* __restrict__ V,
    float* __restrict__ out)
{
    __shared__ unsigned short At[128 * 32];  // chunk c=ks*128+row, 8 shorts each
    __shared__ unsigned short Bt[128 * 32];

    const int tid = threadIdx.x;
    const int lane = tid & 63;
    const int wave = tid >> 6;

    // XCD-aware swizzle: 1024 blocks, 8 XCDs, 128 contiguous per XCD (bijective)
    const int bid = blockIdx.x;
    const int swz = (bid & 7) * 128 + (bid >> 3);
    const int by = swz >> 5;
    const int bx = swz & 31;
    const int brow = by * 128;
    const int bcol = bx * 128;
    const int wr = wave >> 1;
    const int wc = wave & 1;

    f32x4 acc[4][4] = {};

    // staging chunk c: row = c & 127, ks = c >> 7; LDS offset = c*8 shorts.
    // thread loads c0 = tid and c1 = 256 + tid.
    const int row_c = tid & 127;           // same for c0 and c1 (256 = 0 mod 128)
    const int ks0 = tid >> 7;              // 0..1
    const int ks1 = ks0 + 2;               // 2..3
    const size_t aOff0 = (size_t)(brow + row_c) * NCOEF + (ks0 << 3);
    const size_t aOff1 = (size_t)(brow + row_c) * NCOEF + (ks1 << 3);
    const size_t bOff0 = (size_t)(bcol + row_c) * NCOEF + (ks0 << 3);
    const size_t bOff1 = (size_t)(bcol + row_c) * NCOEF + (ks1 << 3);
    // wave-uniform LDS dests (HW adds lane*16B)
    unsigned short* dA0 = At + (wave << 9);
    unsigned short* dA1 = At + 2048 + (wave << 9);
    unsigned short* dB0 = Bt + (wave << 9);
    unsigned short* dB1 = Bt + 2048 + (wave << 9);

    // fragment read: lane l, frag f -> row = wr*64 + f*16 + (l&15), ks = l>>4
    // LDS offset = (ks*128 + row) * 8 shorts
    const int fr = lane & 15;
    const int fks = lane >> 4;
    const unsigned short* aRd = At + ((fks * 128 + wr * 64 + fr) << 3);
    const unsigned short* bRd = Bt + ((fks * 128 + wc * 64 + fr) << 3);

    for (int k0 = 0; k0 < NCOEF; k0 += 32) {
        __builtin_amdgcn_global_load_lds(
            (const __attribute__((address_space(1))) void*)(U + aOff0 + k0),
            (__attribute__((address_space(3))) void*)dA0, 16, 0, 0);
        __builtin_amdgcn_global_load_lds(
            (const __attribute__((address_space(1))) void*)(U + aOff1 + k0),
            (__attribute__((address_space(3))) void*)dA1, 16, 0, 0);
        __builtin_amdgcn_global_load_lds(
            (const __attribute__((address_space(1))) void*)(V + bOff0 + k0),
            (__attribute__((address_space(3))) void*)dB0, 16, 0, 0);
        __builtin_amdgcn_global_load_lds(
            (const __attribute__((address_space(1))) void*)(V + bOff1 + k0),
            (__attribute__((address_space(3))) void*)dB1, 16, 0, 0);
        __syncthreads();  // compiler drains vmcnt before barrier

        bf16x8 a[4], b[4];
        #pragma unroll
        for (int f = 0; f < 4; ++f) {
            a[f] = *(const bf16x8*)(aRd + (f << 7));   // f*16 rows = 128 shorts
            b[f] = *(const bf16x8*)(bRd + (f << 7));
        }
        #pragma unroll
        for (int fm = 0; fm < 4; ++fm)
            #pragma unroll
            for (int fn = 0; fn < 4; ++fn)
                acc[fm][fn] = __builtin_amdgcn_mfma_f32_16x16x32_bf16(
                    a[fm], b[fn], acc[fm][fn], 0, 0, 0);
        __syncthreads();  // protect LDS before next stage
    }

    // epilogue: out = W + acc  (alpha folded into V)
    // C/D layout: col = lane&15, row = (lane>>4)*4 + reg
    const int col0 = bcol + wc * 64 + fr;
    const int row0 = brow + wr * 64 + ((lane >> 4) << 2);
    #pragma unroll
    for (int fm = 0; fm < 4; ++fm) {
        #pragma unroll
        for (int fn = 0; fn < 4; ++fn) {
            const int cc = col0 + fn * 16;
            const int rr = row0 + fm * 16;
            #pragma unroll
            for (int j = 0; j < 4; ++j) {
                const size_t o = (size_t)(rr + j) * NDIM + cc;
                out[o] = W[o] + acc[fm][fn][j];
            }
        }
    }
}

extern "C" void kernel_launch(void* const* d_in, const int* in_sizes, int n_in,
                              void* d_out, int out_size, void* d_ws, size_t ws_size,
                              hipStream_t stream) {
    const float* weight = (const float*)d_in[0];
    const float* dw     = (const float*)d_in[1];
    const int*   fidx   = (const int*)d_in[2];
    float* out = (float*)d_out;

    char* ws = (char*)d_ws;
    unsigned short* U = (unsigned short*)ws;                       // 6,291,456 B
    unsigned short* V = (unsigned short*)(ws + 6291456);           // 6,291,456 B
    char* meta = ws + 2 * 6291456;
    int*   r_m  = (int*)(meta);
    int*   c_m  = (int*)(meta + NCOEF * 4);
    float* su_m = (float*)(meta + NCOEF * 8);
    float* sv_m = (float*)(meta + NCOEF * 12);

    meta_kernel<<<1, NCOEF, 0, stream>>>(fidx, dw, r_m, c_m, su_m, sv_m);
    fill_uv<<<MDIM * 3, 256, 0, stream>>>(r_m, c_m, su_m, sv_m, U, V);
    gemm_kernel<<<1024, 256, 0, stream>>>(weight, U, V, out);
}

// Round 3
// 79.591 us; speedup vs baseline: 1.5213x; 1.2565x over previous
//
#include <hip/hip_runtime.h>

#define MDIM 4096
#define NDIM 4096
#define NCOEF 768
#define ALPHA 16.0f

typedef __attribute__((ext_vector_type(8))) short bf16x8;
typedef __attribute__((ext_vector_type(4))) float f32x4;

__device__ __forceinline__ unsigned short f2bf(float x) {
    unsigned u = __float_as_uint(x);
    u += 0x7FFFu + ((u >> 16) & 1u);
    return (unsigned short)(u >> 16);
}

// ---- kernel 0: per-coefficient metadata (r, c, scales, dedup) ----
__global__ void meta_kernel(const int* __restrict__ fidx,
                            const float* __restrict__ dw,
                            int* __restrict__ r_m, int* __restrict__ c_m,
                            float* __restrict__ su_m, float* __restrict__ sv_m)
{
    __shared__ int idx_s[NCOEF];
    const int p = threadIdx.x;
    idx_s[p] = fidx[p];
    __syncthreads();
    const int idx = idx_s[p];
    // .at[].set semantics: last write wins -> kill earlier duplicates.
    int keep = 1;
    #pragma unroll 16
    for (int q = 0; q < NCOEF; ++q)
        keep &= (q <= p) | (idx_s[q] != idx);
    const int r = idx >> 12;          // / 4096
    const int c = idx & (NDIM - 1);   // % 4096
    const float s0 = 0.015625f;              // sqrt(1/4096)
    const float s1 = 0.022097086912079612f;  // sqrt(2/4096)
    r_m[p] = r;
    c_m[p] = c;
    su_m[p] = (r == 0) ? s0 : s1;
    sv_m[p] = (float)keep * ALPHA * dw[p] * ((c == 0) ? s0 : s1);
}

// ---- kernel 1: materialize U,V in PANEL layout ----
// U_p[((panel*96 + kc)*128 + row)*8 + pi] = s(r_p)*cos(pi*(2i+1)*r_p/8192)
// where i = panel*128+row, p = kc*8+pi. One block per (panel,kc): writes
// 1024 u16 = 2 KB contiguous per array. Integer-exact range reduction.
__global__ __launch_bounds__(256) void fill_uv(
    const int* __restrict__ r_m, const int* __restrict__ c_m,
    const float* __restrict__ su_m, const float* __restrict__ sv_m,
    unsigned short* __restrict__ U, unsigned short* __restrict__ V)
{
    const int b = blockIdx.x;            // b = panel*96 + kc, 0..3071
    const int panel = b / 96;
    const int kc = b - panel * 96;
    const int t = threadIdx.x;
    const int row = (panel << 7) + (t >> 1);
    const int p0 = (kc << 3) + ((t & 1) << 2);
    const unsigned tt = 2u * (unsigned)row + 1u;
    const float w = 3.14159265358979323846f / 8192.0f;
    unsigned short uo[4], vo[4];
    #pragma unroll
    for (int j = 0; j < 4; ++j) {
        const int p = p0 + j;
        const unsigned nu = (tt * (unsigned)r_m[p]) & 16383u;
        const unsigned nv = (tt * (unsigned)c_m[p]) & 16383u;
        uo[j] = f2bf(su_m[p] * cosf((float)nu * w));
        vo[j] = f2bf(sv_m[p] * cosf((float)nv * w));
    }
    const size_t o = (size_t)b * 1024 + (size_t)t * 4;
    *(ushort4*)(U + o) = *(const ushort4*)uo;
    *(ushort4*)(V + o) = *(const ushort4*)vo;
}

// ---- kernel 2: out = W + U @ V^T  (M=N=4096, K=768) ----
// 128x128 tile, BK=32, 4 waves (2x2), each wave 64x64 = 4x4 frags of 16x16x32.
// Panel-major global layout makes each K-tile's staged region 8 KB CONTIGUOUS
// and linearly equal to the k-outer LDS layout: chunk c = ks*128+row at LDS
// offset c*16B. Staging: src = base + tid*16B (coalesced 1 KB/wave/instr),
// dest = linear (global_load_lds-compatible). Fragment reads (16 lanes x
// consecutive rows) are 256B-contiguous -> bank-conflict-free.
__global__ __launch_bounds__(256, 4) void gemm_kernel(
    const float* __restrict__ W,
    const unsigned short* __restrict__ U,
    const unsigned short* __restrict__ V,
    float* __restrict__ out)
{
    __shared__ unsigned short At[128 * 32];  // chunk c=ks*128+row, 8 shorts each
    __shared__ unsigned short Bt[128 * 32];

    const int tid = threadIdx.x;
    const int lane = tid & 63;
    const int wave = tid >> 6;

    // XCD-aware swizzle: 1024 blocks, 8 XCDs, 128 contiguous per XCD (bijective)
    const int bid = blockIdx.x;
    const int swz = (bid & 7) * 128 + (bid >> 3);
    const int by = swz >> 5;
    const int bx = swz & 31;
    const int brow = by * 128;
    const int bcol = bx * 128;
    const int wr = wave >> 1;
    const int wc = wave & 1;

    f32x4 acc[4][4] = {};

    // staged-region bases for this block's row/col panel (u16 units)
    const unsigned short* uPan = U + (size_t)by * 96 * 1024;
    const unsigned short* vPan = V + (size_t)bx * 96 * 1024;
    const size_t off0 = (size_t)tid * 8;          // chunk tid
    const size_t off1 = (size_t)(256 + tid) * 8;  // chunk 256+tid
    // wave-uniform LDS dests (HW adds lane*16B)
    unsigned short* dA0 = At + (wave << 9);
    unsigned short* dA1 = At + 2048 + (wave << 9);
    unsigned short* dB0 = Bt + (wave << 9);
    unsigned short* dB1 = Bt + 2048 + (wave << 9);

    // fragment read: lane l, frag f -> row = w*64 + f*16 + (l&15), ks = l>>4
    const int fr = lane & 15;
    const int fks = lane >> 4;
    const unsigned short* aRd = At + ((fks * 128 + wr * 64 + fr) << 3);
    const unsigned short* bRd = Bt + ((fks * 128 + wc * 64 + fr) << 3);

    for (int ks = 0; ks < 24; ++ks) {
        const unsigned short* uSrc = uPan + (size_t)ks * 4096;
        const unsigned short* vSrc = vPan + (size_t)ks * 4096;
        __builtin_amdgcn_global_load_lds(
            (const __attribute__((address_space(1))) void*)(uSrc + off0),
            (__attribute__((address_space(3))) void*)dA0, 16, 0, 0);
        __builtin_amdgcn_global_load_lds(
            (const __attribute__((address_space(1))) void*)(uSrc + off1),
            (__attribute__((address_space(3))) void*)dA1, 16, 0, 0);
        __builtin_amdgcn_global_load_lds(
            (const __attribute__((address_space(1))) void*)(vSrc + off0),
            (__attribute__((address_space(3))) void*)dB0, 16, 0, 0);
        __builtin_amdgcn_global_load_lds(
            (const __attribute__((address_space(1))) void*)(vSrc + off1),
            (__attribute__((address_space(3))) void*)dB1, 16, 0, 0);
        __syncthreads();  // compiler drains vmcnt before barrier

        bf16x8 a[4], b[4];
        #pragma unroll
        for (int f = 0; f < 4; ++f) {
            a[f] = *(const bf16x8*)(aRd + (f << 7));   // f*16 rows = 128 shorts
            b[f] = *(const bf16x8*)(bRd + (f << 7));
        }
        #pragma unroll
        for (int fm = 0; fm < 4; ++fm)
            #pragma unroll
            for (int fn = 0; fn < 4; ++fn)
                acc[fm][fn] = __builtin_amdgcn_mfma_f32_16x16x32_bf16(
                    a[fm], b[fn], acc[fm][fn], 0, 0, 0);
        __syncthreads();  // protect LDS before next stage
    }

    // epilogue: out = W + acc  (alpha folded into V)
    // C/D layout: col = lane&15, row = (lane>>4)*4 + reg
    const int col0 = bcol + wc * 64 + fr;
    const int row0 = brow + wr * 64 + ((lane >> 4) << 2);
    #pragma unroll
    for (int fm = 0; fm < 4; ++fm) {
        #pragma unroll
        for (int fn = 0; fn < 4; ++fn) {
            const int cc = col0 + fn * 16;
            const int rr = row0 + fm * 16;
            #pragma unroll
            for (int j = 0; j < 4; ++j) {
                const size_t o = (size_t)(rr + j) * NDIM + cc;
                out[o] = W[o] + acc[fm][fn][j];
            }
        }
    }
}

extern "C" void kernel_launch(void* const* d_in, const int* in_sizes, int n_in,
                              void* d_out, int out_size, void* d_ws, size_t ws_size,
                              hipStream_t stream) {
    const float* weight = (const float*)d_in[0];
    const float* dw     = (const float*)d_in[1];
    const int*   fidx   = (const int*)d_in[2];
    float* out = (float*)d_out;

    char* ws = (char*)d_ws;
    unsigned short* U = (unsigned short*)ws;                       // 6,291,456 B
    unsigned short* V = (unsigned short*)(ws + 6291456);           // 6,291,456 B
    char* meta = ws + 2 * 6291456;
    int*   r_m  = (int*)(meta);
    int*   c_m  = (int*)(meta + NCOEF * 4);
    float* su_m = (float*)(meta + NCOEF * 8);
    float* sv_m = (float*)(meta + NCOEF * 12);

    meta_kernel<<<1, NCOEF, 0, stream>>>(fidx, dw, r_m, c_m, su_m, sv_m);
    fill_uv<<<32 * 96, 256, 0, stream>>>(r_m, c_m, su_m, sv_m, U, V);
    gemm_kernel<<<1024, 256, 0, stream>>>(weight, U, V, out);
}

// Round 4
// 75.899 us; speedup vs baseline: 1.5953x; 1.0487x over previous
//
#include <hip/hip_runtime.h>

#define MDIM 4096
#define NDIM 4096
#define NCOEF 768
#define ALPHA 16.0f

typedef __attribute__((ext_vector_type(8))) short bf16x8;
typedef __attribute__((ext_vector_type(4))) float f32x4;

__device__ __forceinline__ unsigned short f2bf(float x) {
    unsigned u = __float_as_uint(x);
    u += 0x7FFFu + ((u >> 16) & 1u);
    return (unsigned short)(u >> 16);
}

__device__ __forceinline__ void glds16(const unsigned short* src, unsigned short* dst) {
    __builtin_amdgcn_global_load_lds(
        (const __attribute__((address_space(1))) void*)src,
        (__attribute__((address_space(3))) void*)dst, 16, 0, 0);
}

// ---- kernel 0: per-coefficient metadata (r, c, scales, dedup) ----
__global__ void meta_kernel(const int* __restrict__ fidx,
                            const float* __restrict__ dw,
                            int* __restrict__ r_m, int* __restrict__ c_m,
                            float* __restrict__ su_m, float* __restrict__ sv_m)
{
    __shared__ int idx_s[NCOEF];
    const int p = threadIdx.x;
    idx_s[p] = fidx[p];
    __syncthreads();
    const int idx = idx_s[p];
    // .at[].set semantics: last write wins -> kill earlier duplicates.
    int keep = 1;
    #pragma unroll 16
    for (int q = 0; q < NCOEF; ++q)
        keep &= (q <= p) | (idx_s[q] != idx);
    const int r = idx >> 12;          // / 4096
    const int c = idx & (NDIM - 1);   // % 4096
    const float s0 = 0.015625f;              // sqrt(1/4096)
    const float s1 = 0.022097086912079612f;  // sqrt(2/4096)
    r_m[p] = r;
    c_m[p] = c;
    su_m[p] = (r == 0) ? s0 : s1;
    sv_m[p] = (float)keep * ALPHA * dw[p] * ((c == 0) ? s0 : s1);
}

// ---- kernel 1: materialize U,V in PANEL layout ----
// U_p[((panel*96 + kc)*128 + row)*8 + pi]; i = panel*128+row, p = kc*8+pi.
// One block per (panel,kc): 2 KB contiguous per array. Integer-exact reduction.
__global__ __launch_bounds__(256) void fill_uv(
    const int* __restrict__ r_m, const int* __restrict__ c_m,
    const float* __restrict__ su_m, const float* __restrict__ sv_m,
    unsigned short* __restrict__ U, unsigned short* __restrict__ V)
{
    const int b = blockIdx.x;            // b = panel*96 + kc, 0..3071
    const int panel = b / 96;
    const int kc = b - panel * 96;
    const int t = threadIdx.x;
    const int row = (panel << 7) + (t >> 1);
    const int p0 = (kc << 3) + ((t & 1) << 2);
    const unsigned tt = 2u * (unsigned)row + 1u;
    const float w = 3.14159265358979323846f / 8192.0f;
    unsigned short uo[4], vo[4];
    #pragma unroll
    for (int j = 0; j < 4; ++j) {
        const int p = p0 + j;
        const unsigned nu = (tt * (unsigned)r_m[p]) & 16383u;
        const unsigned nv = (tt * (unsigned)c_m[p]) & 16383u;
        uo[j] = f2bf(su_m[p] * cosf((float)nu * w));
        vo[j] = f2bf(sv_m[p] * cosf((float)nv * w));
    }
    const size_t o = (size_t)b * 1024 + (size_t)t * 4;
    *(ushort4*)(U + o) = *(const ushort4*)uo;
    *(ushort4*)(V + o) = *(const ushort4*)vo;
}

// ---- kernel 2: out = W + U @ V^T  (M=N=4096, K=768) ----
// 128x128 tile, BK=32, 4 waves (2x2). Double-buffered LDS + raw barriers +
// counted vmcnt(4): tile t+1's stage stays in flight across the barrier and
// its latency hides under tile t's ds_read+MFMA. MFMA operands SWAPPED
// (mfma(b,a)) so each lane's 4 acc regs are 4 consecutive out columns ->
// float4 epilogue for both W read and out write.
__global__ __launch_bounds__(256, 4) void gemm_kernel(
    const float* __restrict__ W,
    const unsigned short* __restrict__ U,
    const unsigned short* __restrict__ V,
    float* __restrict__ out)
{
    __shared__ unsigned short At[2 * 4096];  // [buf][chunk c=ks*128+row][8]
    __shared__ unsigned short Bt[2 * 4096];

    const int tid = threadIdx.x;
    const int lane = tid & 63;
    const int wave = tid >> 6;

    // XCD-aware swizzle: 1024 blocks, 8 XCDs, 128 contiguous per XCD
    const int bid = blockIdx.x;
    const int swz = (bid & 7) * 128 + (bid >> 3);
    const int by = swz >> 5;
    const int bx = swz & 31;
    const int brow = by * 128;
    const int bcol = bx * 128;
    const int wr = wave >> 1;
    const int wc = wave & 1;

    f32x4 acc[4][4] = {};

    const unsigned short* uPan = U + (size_t)by * 96 * 1024;
    const unsigned short* vPan = V + (size_t)bx * 96 * 1024;
    const size_t off0 = (size_t)tid * 8;
    const size_t off1 = (size_t)(256 + tid) * 8;
    const int wofs = wave << 9;   // wave-uniform LDS dest offset (u16)

    // fragment read: lane l, frag f -> row = w*64 + f*16 + (l&15), ks = l>>4
    const int fr = lane & 15;
    const int fks = lane >> 4;
    const int aRdO = (fks * 128 + wr * 64 + fr) << 3;
    const int bRdO = (fks * 128 + wc * 64 + fr) << 3;

#define STAGE(ks, buf) do {                                              \
        const unsigned short* uS = uPan + (size_t)(ks) * 4096;           \
        const unsigned short* vS = vPan + (size_t)(ks) * 4096;           \
        unsigned short* aD = At + (buf) * 4096;                          \
        unsigned short* bD = Bt + (buf) * 4096;                          \
        glds16(uS + off0, aD + wofs);                                    \
        glds16(uS + off1, aD + 2048 + wofs);                             \
        glds16(vS + off0, bD + wofs);                                    \
        glds16(vS + off1, bD + 2048 + wofs);                             \
    } while (0)

#define COMPUTE(buf) do {                                                \
        const unsigned short* aB = At + (buf) * 4096 + aRdO;             \
        const unsigned short* bB = Bt + (buf) * 4096 + bRdO;             \
        bf16x8 a[4], b[4];                                               \
        _Pragma("unroll")                                                \
        for (int f = 0; f < 4; ++f) {                                    \
            a[f] = *(const bf16x8*)(aB + (f << 7));                      \
            b[f] = *(const bf16x8*)(bB + (f << 7));                      \
        }                                                                \
        _Pragma("unroll")                                                \
        for (int fm = 0; fm < 4; ++fm)                                   \
            _Pragma("unroll")                                            \
            for (int fn = 0; fn < 4; ++fn)                               \
                acc[fm][fn] = __builtin_amdgcn_mfma_f32_16x16x32_bf16(   \
                    b[fn], a[fm], acc[fm][fn], 0, 0, 0);                 \
    } while (0)

    STAGE(0, 0);
    int cur = 0;
    #pragma unroll 1
    for (int t = 0; t < 23; ++t) {
        STAGE(t + 1, cur ^ 1);
        // wait for tile t's 4 loads only; t+1's 4 stay in flight
        asm volatile("s_waitcnt vmcnt(4)" ::: "memory");
        __builtin_amdgcn_s_barrier();
        asm volatile("" ::: "memory");
        COMPUTE(cur);
        // drain LDS reads before next STAGE may overwrite this buffer
        asm volatile("s_waitcnt lgkmcnt(0)" ::: "memory");
        __builtin_amdgcn_s_barrier();
        asm volatile("" ::: "memory");
        cur ^= 1;
    }
    asm volatile("s_waitcnt vmcnt(0)" ::: "memory");
    __builtin_amdgcn_s_barrier();
    asm volatile("" ::: "memory");
    COMPUTE(cur);

    // epilogue: out = W + acc (alpha folded into V). Swapped-operand C/D
    // layout: lane holds row = lane&15 (fixed), cols = (lane>>4)*4 .. +3
    // consecutive -> float4 loads/stores.
    const int erow = brow + wr * 64 + fr;
    const int ecol = bcol + wc * 64 + ((lane >> 4) << 2);
    #pragma unroll
    for (int fm = 0; fm < 4; ++fm) {
        #pragma unroll
        for (int fn = 0; fn < 4; ++fn) {
            const size_t o = (size_t)(erow + fm * 16) * NDIM + (ecol + fn * 16);
            const float4 w4 = *(const float4*)(W + o);
            float4 r4;
            r4.x = w4.x + acc[fm][fn][0];
            r4.y = w4.y + acc[fm][fn][1];
            r4.z = w4.z + acc[fm][fn][2];
            r4.w = w4.w + acc[fm][fn][3];
            *(float4*)(out + o) = r4;
        }
    }
#undef STAGE
#undef COMPUTE
}

extern "C" void kernel_launch(void* const* d_in, const int* in_sizes, int n_in,
                              void* d_out, int out_size, void* d_ws, size_t ws_size,
                              hipStream_t stream) {
    const float* weight = (const float*)d_in[0];
    const float* dw     = (const float*)d_in[1];
    const int*   fidx   = (const int*)d_in[2];
    float* out = (float*)d_out;

    char* ws = (char*)d_ws;
    unsigned short* U = (unsigned short*)ws;                       // 6,291,456 B
    unsigned short* V = (unsigned short*)(ws + 6291456);           // 6,291,456 B
    char* meta = ws + 2 * 6291456;
    int*   r_m  = (int*)(meta);
    int*   c_m  = (int*)(meta + NCOEF * 4);
    float* su_m = (float*)(meta + NCOEF * 8);
    float* sv_m = (float*)(meta + NCOEF * 12);

    meta_kernel<<<1, NCOEF, 0, stream>>>(fidx, dw, r_m, c_m, su_m, sv_m);
    fill_uv<<<32 * 96, 256, 0, stream>>>(r_m, c_m, su_m, sv_m, U, V);
    gemm_kernel<<<1024, 256, 0, stream>>>(weight, U, V, out);
}